// Round 12
// baseline (567.103 us; speedup 1.0000x reference)
//
#include <hip/hip_runtime.h>
#include <hip/hip_bf16.h>

// ---------------------------------------------------------------------------
// MoE dense all-expert forward, MI355X / gfx950.  B=16384, D=H=O=256, E=32.
// Round 16: STREAM-BANDWIDTH HALVING (the unified R0-R15 model).
//  Every clean variant ran at weight_bytes / 9-12 TB/s (R0 8.7, R13 10.0,
//  R6 12.4, R14 8.9 TB/s) regardless of schedule: the kernel is bound by
//  the L2/L3 service rate of the shared weight stream; LDS (40us) and MFMA
//  (58us) hide under it. So: halve the bytes.
//  - 256 blocks = 128 row-tiles x 2 expert-halves; block = 128 rows x 16
//    experts -> each weight byte feeds 2x FLOPs -> stream 2.1 -> 1.06 GB.
//  - 8 waves; wave owns 32 cols x all 128 rows for BOTH GEMMs.
//    acc: oacc 64 (persistent) + hacc 64 (phase-transient) = 128 AGPR;
//    arch ~90 -> fits the observed 128 VGPR + 128 AGPR budget.
//  - LDS: x_s 64 KB + h_s 64 KB (single) + gws 8.7 KB = 137 KB, 1 blk/CU.
//  - Phase e: [GEMM1 -> h_s] bar [GEMM2 from h_s] bar.  16 phases.
//    Weight rings (depth 4) flow ACROSS barriers: W1 refills issued late in
//    phase A land during phase B (full-phase latency cover) and vice versa.
//    x B-ring self-priming (&15 wrap = x is expert-invariant); h B-ring
//    re-prologued per phase (h changes), refills guarded ks<14.
//  - Expert-half combine: hipMemsetAsync(out,0) + atomicAdd f32 (2
//    commutative adds/element -> deterministic).  b2 folded into oacc init.
// ---------------------------------------------------------------------------

typedef __attribute__((ext_vector_type(8))) short bf16x8;   // 8 bf16 = 4 VGPRs
typedef __attribute__((ext_vector_type(4))) float f32x4;
typedef __attribute__((ext_vector_type(16))) float f32x16;  // 32x32 C frag

__device__ __forceinline__ unsigned short f2bf(float f) {
    unsigned u = __builtin_bit_cast(unsigned, f);
    u += 0x7FFFu + ((u >> 16) & 1u);        // round-to-nearest-even
    return (unsigned short)(u >> 16);
}
__device__ __forceinline__ unsigned pack_bf16x2(float a, float b) {
    return (unsigned)f2bf(a) | ((unsigned)f2bf(b) << 16);
}

// 16B-chunk XOR swizzle for [rows][256 elem] bf16 tiles (index in ushorts)
#define LX(r, ch) (((r) << 8) + ((((ch) ^ ((r) & 7))) << 3))

// ------------------- W f32 -> bf16 convert + tile reorder ------------------
// Stream s = m*8 + cg: m=0 -> W1 rows cg*32..+31, m=1 -> W2 rows cg*32..+31.
// Per stream: 33 experts (e=32 = prefetch-overrun pad) x 16 k-chunks of
// 512 bf16 (1 KB): elem (lane, j): row = cg*32 + (lane&31),
// k = ks*16 + (lane>>5)*8 + j  — the mfma_32x32x16 A-frag order.
__global__ __launch_bounds__(256) void cvt_w(const float* __restrict__ W1,
                                             const float* __restrict__ W2,
                                             unsigned short* __restrict__ Wr) {
    int T = blockIdx.x * 256 + threadIdx.x;          // 524288 threads
    int lane = T & 63, ks = (T >> 6) & 15, e = (T >> 10) & 31;
    int cg = (T >> 15) & 7, m = (T >> 18) & 1;
    int l31 = lane & 31, hi = lane >> 5;
    const float* src = (m ? W2 : W1) +
                       ((long)e * 256 + cg * 32 + l31) * 256 + ks * 16 + hi * 8;
    float4 v0 = ((const float4*)src)[0], v1 = ((const float4*)src)[1];
    uint4 o;
    o.x = pack_bf16x2(v0.x, v0.y); o.y = pack_bf16x2(v0.z, v0.w);
    o.z = pack_bf16x2(v1.x, v1.y); o.w = pack_bf16x2(v1.z, v1.w);
    long U = (((long)(m * 8 + cg) * 33 + e) * 16 + ks) * 64 + lane;
    ((uint4*)Wr)[U] = o;
}

#define MFMA32(A, B, C) __builtin_amdgcn_mfma_f32_32x32x16_bf16(A, B, C, 0, 0, 0)

// GEMM1 k-step (ks literal 0..15): A-ring slot ks&3 (loaded 4 steps/one
// phase ago), refill from bumped W1 ptr; x B-ring depth 2, self-priming
// (&15 wrap valid: x expert-invariant). 4 MFMAs (4 row-groups).
#define ASTEP(ks) do {                                                         \
    bf16x8 a = r1[(ks) & 3];                                                   \
    r1[(ks) & 3] = *(const bf16x8*)(p1 + ((ks) & 3) * 512);                    \
    _Pragma("unroll")                                                          \
    for (int rg = 0; rg < 4; ++rg) {                                           \
        bf16x8 b = xb[(ks) & 1][rg];                                           \
        xb[(ks) & 1][rg] = *(const bf16x8*)                                    \
            (&x_s[LX(rg * 32 + l31, ((((ks) + 2) & 15) * 2) + hi)]);           \
        hacc[rg] = MFMA32(a, b, hacc[rg]);                                     \
    }                                                                          \
    if (((ks) & 3) == 3) { p1 += 2048; }                                       \
} while (0)

// GEMM2 k-step: A-ring from W2; h B-ring depth 2, per-phase prologue,
// refills only while in range (h changes each phase).
#define BSTEP(ks) do {                                                         \
    bf16x8 a = r2[(ks) & 3];                                                   \
    r2[(ks) & 3] = *(const bf16x8*)(p2 + ((ks) & 3) * 512);                    \
    _Pragma("unroll")                                                          \
    for (int rg = 0; rg < 4; ++rg) {                                           \
        bf16x8 b = hb[(ks) & 1][rg];                                           \
        if ((ks) < 14)                                                         \
            hb[(ks) & 1][rg] = *(const bf16x8*)                                \
                (&h_s[LX(rg * 32 + l31, (((ks) + 2) * 2) + hi)]);              \
        oacc[rg] = MFMA32(a, b, oacc[rg]);                                     \
    }                                                                          \
    if (((ks) & 3) == 3) { p2 += 2048; }                                       \
} while (0)

__global__ __launch_bounds__(512)
__attribute__((amdgpu_waves_per_eu(2, 2)))
void moe_kernel(
    const float* __restrict__ x,
    const unsigned short* __restrict__ Wr,
    const float* __restrict__ bias1,
    const float* __restrict__ b2,
    const float* __restrict__ Wg,
    const float* __restrict__ bg,
    float* __restrict__ out)
{
    __shared__ __align__(16) unsigned short x_s[128 * 256];     // 64 KB
    __shared__ __align__(16) unsigned short h_s[128 * 256];     // 64 KB
    __shared__ float gws[128 * 17];                             // 8.5 KB

    const int tid  = threadIdx.x;
    const int wv   = tid >> 6, lane = tid & 63;
    const int l31  = lane & 31, hi = lane >> 5;
    const int cg   = wv;                        // cols cg*32 .. cg*32+31
    const int row0 = (blockIdx.x >> 1) * 128;   // 128-row tile
    const int e0   = (blockIdx.x & 1) * 16;     // expert half

    // ---- stage x tile: f32 global -> bf16 LDS (swizzled), 128 rows ----
#pragma unroll
    for (int c = 0; c < 8; ++c) {
        int chunk = tid + c * 512;              // 4096 chunks of 8 elems
        int r = chunk >> 5, ch = chunk & 31;
        const float4* s = (const float4*)(x + (long)(row0 + r) * 256 + ch * 8);
        float4 v0 = s[0], v1 = s[1];
        uint4 o;
        o.x = pack_bf16x2(v0.x, v0.y); o.y = pack_bf16x2(v0.z, v0.w);
        o.z = pack_bf16x2(v1.x, v1.y); o.w = pack_bf16x2(v1.z, v1.w);
        *(uint4*)(&x_s[LX(r, ch)]) = o;
    }

    // ---- inline gating: 16 rows/wave, full 32-expert softmax+top22;
    //      keep this block's 16 expert weights ----
    {
        const int e32 = lane & 31, half = lane >> 5;
        const float4* wg4 = (const float4*)(Wg + e32 * 256 + half * 128);
        float bgv = bg[e32];
        for (int i = 0; i < 16; ++i) {
            int lr = wv * 16 + i;
            const float4* xr4 = (const float4*)(x + (long)(row0 + lr) * 256 + half * 128);
            float acc = 0.f;
#pragma unroll
            for (int tt = 0; tt < 32; ++tt) {
                float4 w = wg4[tt], xv = xr4[tt];
                acc = fmaf(w.x, xv.x, acc); acc = fmaf(w.y, xv.y, acc);
                acc = fmaf(w.z, xv.z, acc); acc = fmaf(w.w, xv.w, acc);
            }
            acc += __shfl_xor(acc, 32);
            float score = (acc + bgv) / 2.71828182845904523f;   // TEMP = e

            float m = score;
#pragma unroll
            for (int d = 16; d >= 1; d >>= 1) m = fmaxf(m, __shfl_xor(m, d));
            float p_ = expf(score - m);
            float ps = p_;
#pragma unroll
            for (int d = 16; d >= 1; d >>= 1) ps += __shfl_xor(ps, d);
            float prob = p_ / ps;

            int rank = 0;
#pragma unroll
            for (int j = 0; j < 32; ++j) {
                float pj = __shfl(prob, j);
                rank += (pj > prob || (pj == prob && j < e32)) ? 1 : 0;
            }
            float kept = (rank < 22) ? prob : 0.f;
            float wsum = kept;
#pragma unroll
            for (int d = 16; d >= 1; d >>= 1) wsum += __shfl_xor(wsum, d);
            float weight = kept / (wsum + 1e-8f);

            if (half == 0 && e32 >= e0 && e32 < e0 + 16)
                gws[lr * 17 + (e32 - e0)] = weight;
        }
    }

    __syncthreads();   // x_s + gws ready

    // ---- weight streams (one W1 + one W2 per wave, 32 cols each) ----
    const unsigned short* w1p =
        Wr + (long)cg * (33 * 16 * 512) + (long)e0 * 8192 + lane * 8;
    const unsigned short* w2p =
        Wr + (long)(8 + cg) * (33 * 16 * 512) + (long)e0 * 8192 + lane * 8;
    bf16x8 r1[4], r2[4];
#pragma unroll
    for (int t = 0; t < 4; ++t) {
        r1[t] = *(const bf16x8*)(w1p + t * 512);
        r2[t] = *(const bf16x8*)(w2p + t * 512);
    }
    const unsigned short* p1 = w1p + 4 * 512;
    const unsigned short* p2 = w2p + 4 * 512;

    // ---- x B-ring (depth 2 x 4 row-groups), self-priming ----
    bf16x8 xb[2][4];
#pragma unroll
    for (int rg = 0; rg < 4; ++rg) {
        xb[0][rg] = *(const bf16x8*)(&x_s[LX(rg * 32 + l31, hi)]);
        xb[1][rg] = *(const bf16x8*)(&x_s[LX(rg * 32 + l31, 2 + hi)]);
    }
    bf16x8 hb[2][4];

    // ---- oacc init = sum_{e in half} gw * b2 ----
    f32x16 oacc[4];
#pragma unroll
    for (int rg = 0; rg < 4; ++rg)
#pragma unroll
        for (int i = 0; i < 16; ++i) oacc[rg][i] = 0.f;
    for (int ee = 0; ee < 16; ++ee) {
#pragma unroll
        for (int q = 0; q < 4; ++q) {
            float4 bb = *(const float4*)(b2 + (e0 + ee) * 256 + cg * 32 + q * 8 + hi * 4);
#pragma unroll
            for (int rg = 0; rg < 4; ++rg) {
                float gv = gws[(rg * 32 + l31) * 17 + ee];
                oacc[rg][4 * q + 0] = fmaf(gv, bb.x, oacc[rg][4 * q + 0]);
                oacc[rg][4 * q + 1] = fmaf(gv, bb.y, oacc[rg][4 * q + 1]);
                oacc[rg][4 * q + 2] = fmaf(gv, bb.z, oacc[rg][4 * q + 2]);
                oacc[rg][4 * q + 3] = fmaf(gv, bb.w, oacc[rg][4 * q + 3]);
            }
        }
    }

    // ---- expert loop: 16 phases, 2 barriers each ----
#pragma unroll 1
    for (int ep = 0; ep < 16; ++ep) {
        const int e = e0 + ep;

        // GEMM1: h(e) = x W1^T for this wave's 32 cols, all 128 rows
        f32x16 hacc[4];
#pragma unroll
        for (int rg = 0; rg < 4; ++rg)
#pragma unroll
            for (int i = 0; i < 16; ++i) hacc[rg][i] = 0.f;

        ASTEP(0);  ASTEP(1);  ASTEP(2);  ASTEP(3);
        ASTEP(4);  ASTEP(5);  ASTEP(6);  ASTEP(7);
        ASTEP(8);  ASTEP(9);  ASTEP(10); ASTEP(11);
        ASTEP(12); ASTEP(13); ASTEP(14); ASTEP(15);

        // epilogue: +b1, relu, *gate, pack -> h_s
#pragma unroll
        for (int rg = 0; rg < 4; ++rg) {
            const int rr = rg * 32 + l31;
            const float gw = gws[rr * 17 + ep];
            const int rbase = rr << 8, rsw = rr & 7;
#pragma unroll
            for (int q = 0; q < 4; ++q) {
                float4 bv = *(const float4*)(bias1 + e * 256 + cg * 32 + q * 8 + hi * 4);
                float v0 = fmaxf(hacc[rg][4 * q + 0] + bv.x, 0.f) * gw;
                float v1 = fmaxf(hacc[rg][4 * q + 1] + bv.y, 0.f) * gw;
                float v2 = fmaxf(hacc[rg][4 * q + 2] + bv.z, 0.f) * gw;
                float v3 = fmaxf(hacc[rg][4 * q + 3] + bv.w, 0.f) * gw;
                uint2 pk;
                pk.x = pack_bf16x2(v0, v1);
                pk.y = pack_bf16x2(v2, v3);
                int ch = cg * 4 + q;
                *(uint2*)(&h_s[rbase + ((ch ^ rsw) << 3) + hi * 4]) = pk;
            }
        }

        asm volatile("s_waitcnt lgkmcnt(0)" ::: "memory");
        __builtin_amdgcn_s_barrier();

        // GEMM2: out += h(e) W2^T.  h B-ring prologue (h changed).
#pragma unroll
        for (int rg = 0; rg < 4; ++rg) {
            hb[0][rg] = *(const bf16x8*)(&h_s[LX(rg * 32 + l31, hi)]);
            hb[1][rg] = *(const bf16x8*)(&h_s[LX(rg * 32 + l31, 2 + hi)]);
        }
        BSTEP(0);  BSTEP(1);  BSTEP(2);  BSTEP(3);
        BSTEP(4);  BSTEP(5);  BSTEP(6);  BSTEP(7);
        BSTEP(8);  BSTEP(9);  BSTEP(10); BSTEP(11);
        BSTEP(12); BSTEP(13); BSTEP(14); BSTEP(15);

        asm volatile("s_waitcnt lgkmcnt(0)" ::: "memory");
        __builtin_amdgcn_s_barrier();   // h_s free for next phase
    }

    // ---- combine: atomic add partial (out pre-zeroed by memset) ----
#pragma unroll
    for (int rg = 0; rg < 4; ++rg) {
#pragma unroll
        for (int q = 0; q < 4; ++q) {
            float* op = out + (long)(row0 + rg * 32 + l31) * 256 +
                        cg * 32 + q * 8 + hi * 4;
            atomicAdd(op + 0, oacc[rg][4 * q + 0]);
            atomicAdd(op + 1, oacc[rg][4 * q + 1]);
            atomicAdd(op + 2, oacc[rg][4 * q + 2]);
            atomicAdd(op + 3, oacc[rg][4 * q + 3]);
        }
    }
}

// ------------------------------- launch ------------------------------------
extern "C" void kernel_launch(void* const* d_in, const int* in_sizes, int n_in,
                              void* d_out, int out_size, void* d_ws, size_t ws_size,
                              hipStream_t stream) {
    (void)in_sizes; (void)n_in; (void)out_size; (void)ws_size;
    const float* x  = (const float*)d_in[0];   // [16384,256]
    const float* W1 = (const float*)d_in[1];   // [32,256,256]
    const float* b1 = (const float*)d_in[2];   // [32,256]
    const float* W2 = (const float*)d_in[3];   // [32,256,256]
    const float* b2 = (const float*)d_in[4];   // [32,256]
    const float* Wg = (const float*)d_in[5];   // [32,256]
    const float* bg = (const float*)d_in[6];   // [32]
    float* out = (float*)d_out;                // [16384,256]

    // ws: Wr = 16 streams x 33 experts x 16 KB = 8.25 MiB (expert 32 = pad)
    unsigned short* Wr = (unsigned short*)d_ws;

    cvt_w<<<2048, 256, 0, stream>>>(W1, W2, Wr);
    hipMemsetAsync(out, 0, (size_t)16384 * 256 * sizeof(float), stream);
    moe_kernel<<<256, 512, 0, stream>>>(x, Wr, b1, b2, Wg, bg, out);
}